// Round 6
// baseline (139.551 us; speedup 1.0000x reference)
//
#include <hip/hip_runtime.h>

#define TT 200
#define NN 512
#define DD 4
#define HH 64
#define LL 32
#define SB 16                // sequences per block (fills MFMA M=16)
#define BPB (NN / SB)        // 32 blocks per batch
#define KP 72                // ushort pitch per h row (144B = 9*16B: b128-alignable)
#define LOG2E 1.44269504088896340736f

typedef short bf16x8 __attribute__((ext_vector_type(8)));
typedef float f32x4 __attribute__((ext_vector_type(4)));

union U8 { unsigned short s[8]; unsigned u[4]; bf16x8 v; };

// f32 -> (hi, lo) bf16 limbs by truncation: x = hi + lo + err, |err| <= 2^-16 |x|
__device__ __forceinline__ void split2(float x, unsigned short& hi, unsigned short& lo) {
    unsigned u = __float_as_uint(x);
    hi = (unsigned short)(u >> 16);
    float lf = x - __uint_as_float(u & 0xffff0000u);
    lo = (unsigned short)(__float_as_uint(lf) >> 16);
}

__global__ __launch_bounds__(256, 1)
void gru_traj_kernel(const float* __restrict__ xg,    // (B,T,N,D)
                     const float* __restrict__ W_ih,  // (192,4)
                     const float* __restrict__ W_hh,  // (192,64)
                     const float* __restrict__ b_ih,  // (192,)
                     const float* __restrict__ b_hh,  // (192,)
                     const float* __restrict__ W_enc, // (32,64)
                     const float* __restrict__ b_enc, // (32,)
                     float* __restrict__ out)         // (B,N,32)
{
    __shared__ __align__(16) unsigned short hhi[2][SB][KP];   // h hi-limbs (dbuf)
    __shared__ __align__(16) unsigned short hlo[2][SB][KP];   // h lo-limbs
    __shared__ __align__(16) unsigned short xhb[TT][SB][DD];  // x hi-limbs (25.6 KB)
    __shared__ __align__(16) unsigned short xlb[TT][SB][DD];  // x lo-limbs (25.6 KB)
    __shared__ __align__(16) float hsf[SB][HH + 4];           // f32 h for epilogue

    const int tid = threadIdx.x;
    const int bid = blockIdx.x;
    const int b   = bid >> 5;                // bid / BPB
    const int n0  = (bid & (BPB - 1)) * SB;

    const int w  = tid >> 6;     // wave -> gate tiles {w, w+4, w+8}: r,z,n for units 16w..16w+15
    const int l  = tid & 63;
    const int lr = l & 15;       // A-row / B-col / C-col within tile
    const int lg = l >> 4;       // k-group (A/B), row-group (C)

    // ---- prologue: load x, split to bf16 limb planes in LDS ----
    for (int f = tid; f < TT * SB; f += 256) {
        const int t = f >> 4, s = f & 15;
        float4 v = *reinterpret_cast<const float4*>(
            xg + ((size_t)(b * TT + t) * NN + n0 + s) * DD);
        unsigned short h0,h1,h2,h3,l0,l1,l2,l3;
        split2(v.x,h0,l0); split2(v.y,h1,l1); split2(v.z,h2,l2); split2(v.w,h3,l3);
        uint2 ph = { (unsigned)h0 | ((unsigned)h1 << 16), (unsigned)h2 | ((unsigned)h3 << 16) };
        uint2 pl = { (unsigned)l0 | ((unsigned)l1 << 16), (unsigned)l2 | ((unsigned)l3 << 16) };
        *reinterpret_cast<uint2*>(&xhb[t][s][0]) = ph;
        *reinterpret_cast<uint2*>(&xlb[t][s][0]) = pl;
    }

    // ---- B fragments: W_hh^T tiles, prescaled (log2e / 2log2e), bf16 hi/lo limbs ----
    const float sc[3] = { LOG2E, LOG2E, 2.0f * LOG2E };
    bf16x8 bh[3][2], bl[3][2];
    #pragma unroll
    for (int i = 0; i < 3; ++i) {
        const int g = i * 64 + 16 * w + lr;
        #pragma unroll
        for (int kc = 0; kc < 2; ++kc) {
            const float* p = W_hh + g * HH + kc * 32 + lg * 8;
            U8 uh, ul;
            #pragma unroll
            for (int j = 0; j < 8; ++j) split2(p[j] * sc[i], uh.s[j], ul.s[j]);
            bh[i][kc] = uh.v; bl[i][kc] = ul.v;
        }
    }
    // ---- B-aug fragments (kc=2): W_ih limbs at k=64..67, bias limbs at k=68; zero elsewhere ----
    bf16x8 bxh[3], bxl[3];
    #pragma unroll
    for (int i = 0; i < 3; ++i) {
        U8 xh, xl;
        #pragma unroll
        for (int j = 0; j < 8; ++j) { xh.s[j] = 0; xl.s[j] = 0; }
        if (lg == 0) {
            const int g = i * 64 + 16 * w + lr;
            #pragma unroll
            for (int d = 0; d < 4; ++d) split2(W_ih[g * DD + d] * sc[i], xh.s[d], xl.s[d]);
            float bias = (i < 2) ? (b_ih[g] + b_hh[g]) * sc[i] : b_ih[g] * sc[i];
            split2(bias, xh.s[4], xl.s[4]);
        }
        bxh[i] = xh.v; bxl[i] = xl.v;
    }
    const float bn = b_hh[2 * 64 + 16 * w + lr] * sc[2];   // ghn bias (n-gate h-part)

    // ---- init: zero h limb buffers (h0 = 0) ----
    for (int idx = tid; idx < 2 * SB * KP / 2; idx += 256) {
        reinterpret_cast<unsigned*>(hhi)[idx] = 0u;
        reinterpret_cast<unsigned*>(hlo)[idx] = 0u;
    }
    float hreg[4] = {0.f, 0.f, 0.f, 0.f};   // h[s = lg*4+r][u = 16w+lr]
    __syncthreads();

    #pragma unroll 2
    for (int t = 0; t < TT; ++t) {
        const int cur = t & 1, nxt = cur ^ 1;

        // ---- A fragments: h limbs (b128) + x-aug (b64 broadcast) ----
        bf16x8 ah0 = *reinterpret_cast<const bf16x8*>(&hhi[cur][lr][lg * 8]);
        bf16x8 ah1 = *reinterpret_cast<const bf16x8*>(&hhi[cur][lr][32 + lg * 8]);
        bf16x8 al0 = *reinterpret_cast<const bf16x8*>(&hlo[cur][lr][lg * 8]);
        bf16x8 al1 = *reinterpret_cast<const bf16x8*>(&hlo[cur][lr][32 + lg * 8]);
        uint2 xh2 = *reinterpret_cast<const uint2*>(&xhb[t][lr][0]);
        uint2 xl2 = *reinterpret_cast<const uint2*>(&xlb[t][lr][0]);
        U8 axh_u, axl_u;
        axh_u.u[0] = xh2.x; axh_u.u[1] = xh2.y; axh_u.u[2] = 0x00003F80u; axh_u.u[3] = 0u;
        axl_u.u[0] = xl2.x; axl_u.u[1] = xl2.y; axl_u.u[2] = 0u;          axl_u.u[3] = 0u;
        bf16x8 axh = axh_u.v, axl = axl_u.v;
        // (lg>=1 lanes carry x-limb data at k-slots where B-aug is zero -> contributes 0)

        // ---- 27 MFMAs: R(9), Z(9), GHN(6), GXN(3) — independent chains ----
        f32x4 aR = {0.f,0.f,0.f,0.f}, aZ = {0.f,0.f,0.f,0.f};
        f32x4 aN = {bn,bn,bn,bn},     aX = {0.f,0.f,0.f,0.f};
        aR = __builtin_amdgcn_mfma_f32_16x16x32_bf16(ah0, bh[0][0], aR, 0,0,0);
        aZ = __builtin_amdgcn_mfma_f32_16x16x32_bf16(ah0, bh[1][0], aZ, 0,0,0);
        aN = __builtin_amdgcn_mfma_f32_16x16x32_bf16(ah0, bh[2][0], aN, 0,0,0);
        aX = __builtin_amdgcn_mfma_f32_16x16x32_bf16(axh, bxh[2],   aX, 0,0,0);
        aR = __builtin_amdgcn_mfma_f32_16x16x32_bf16(ah1, bh[0][1], aR, 0,0,0);
        aZ = __builtin_amdgcn_mfma_f32_16x16x32_bf16(ah1, bh[1][1], aZ, 0,0,0);
        aN = __builtin_amdgcn_mfma_f32_16x16x32_bf16(ah1, bh[2][1], aN, 0,0,0);
        aX = __builtin_amdgcn_mfma_f32_16x16x32_bf16(axl, bxh[2],   aX, 0,0,0);
        aR = __builtin_amdgcn_mfma_f32_16x16x32_bf16(axh, bxh[0],   aR, 0,0,0);
        aZ = __builtin_amdgcn_mfma_f32_16x16x32_bf16(axh, bxh[1],   aZ, 0,0,0);
        aN = __builtin_amdgcn_mfma_f32_16x16x32_bf16(al0, bh[2][0], aN, 0,0,0);
        aX = __builtin_amdgcn_mfma_f32_16x16x32_bf16(axh, bxl[2],   aX, 0,0,0);
        aR = __builtin_amdgcn_mfma_f32_16x16x32_bf16(al0, bh[0][0], aR, 0,0,0);
        aZ = __builtin_amdgcn_mfma_f32_16x16x32_bf16(al0, bh[1][0], aZ, 0,0,0);
        aN = __builtin_amdgcn_mfma_f32_16x16x32_bf16(al1, bh[2][1], aN, 0,0,0);
        aR = __builtin_amdgcn_mfma_f32_16x16x32_bf16(al1, bh[0][1], aR, 0,0,0);
        aZ = __builtin_amdgcn_mfma_f32_16x16x32_bf16(al1, bh[1][1], aZ, 0,0,0);
        aN = __builtin_amdgcn_mfma_f32_16x16x32_bf16(ah0, bl[2][0], aN, 0,0,0);
        aR = __builtin_amdgcn_mfma_f32_16x16x32_bf16(axl, bxh[0],   aR, 0,0,0);
        aZ = __builtin_amdgcn_mfma_f32_16x16x32_bf16(axl, bxh[1],   aZ, 0,0,0);
        aN = __builtin_amdgcn_mfma_f32_16x16x32_bf16(ah1, bl[2][1], aN, 0,0,0);
        aR = __builtin_amdgcn_mfma_f32_16x16x32_bf16(ah0, bl[0][0], aR, 0,0,0);
        aZ = __builtin_amdgcn_mfma_f32_16x16x32_bf16(ah0, bl[1][0], aZ, 0,0,0);
        aR = __builtin_amdgcn_mfma_f32_16x16x32_bf16(ah1, bl[0][1], aR, 0,0,0);
        aZ = __builtin_amdgcn_mfma_f32_16x16x32_bf16(ah1, bl[1][1], aZ, 0,0,0);
        aR = __builtin_amdgcn_mfma_f32_16x16x32_bf16(axh, bxl[0],   aR, 0,0,0);
        aZ = __builtin_amdgcn_mfma_f32_16x16x32_bf16(axh, bxl[1],   aZ, 0,0,0);

        // ---- gates (exp2 domain) + h update, split at writer ----
        #pragma unroll
        for (int r = 0; r < 4; ++r) {
            const int s = lg * 4 + r;
            const int u = 16 * w + lr;
            float rg = __builtin_amdgcn_rcpf(1.0f + exp2f(-aR[r]));
            float z  = __builtin_amdgcn_rcpf(1.0f + exp2f(-aZ[r]));
            float na = fmaf(rg, aN[r], aX[r]);          // = 2*log2e * tanh-arg
            na = fminf(fmaxf(na, -44.0f), 44.0f);
            float e  = exp2f(-na);
            float nn = (1.0f - e) * __builtin_amdgcn_rcpf(1.0f + e);
            float hn = fmaf(z, hreg[r] - nn, nn);       // (1-z)n + z h
            hreg[r] = hn;
            unsigned short hi, lo;
            split2(hn, hi, lo);
            hhi[nxt][s][u] = hi;
            hlo[nxt][s][u] = lo;
        }
        __syncthreads();   // h_{t+1} limbs visible; buf[cur] free next iteration
    }

    // ---- epilogue: out = h @ W_enc^T + b_enc (512 outputs, 256 threads -> strided) ----
    #pragma unroll
    for (int r = 0; r < 4; ++r)
        hsf[lg * 4 + r][16 * w + lr] = hreg[r];
    __syncthreads();
    for (int o = tid; o < SB * LL; o += 256) {
        const int s = o >> 5, li = o & 31;
        float a = b_enc[li];
        #pragma unroll
        for (int k = 0; k < HH; ++k)
            a = fmaf(hsf[s][k], W_enc[li * HH + k], a);
        out[(bid * SB + s) * LL + li] = a;
    }
}

extern "C" void kernel_launch(void* const* d_in, const int* in_sizes, int n_in,
                              void* d_out, int out_size, void* d_ws, size_t ws_size,
                              hipStream_t stream) {
    const float* xg    = (const float*)d_in[0];
    const float* W_ih  = (const float*)d_in[1];
    const float* W_hh  = (const float*)d_in[2];
    const float* b_ih  = (const float*)d_in[3];
    const float* b_hh  = (const float*)d_in[4];
    const float* W_enc = (const float*)d_in[5];
    const float* b_enc = (const float*)d_in[6];
    float* out = (float*)d_out;

    dim3 grid(8 * BPB), block(256);   // 256 blocks -> exactly 1 block/CU
    hipLaunchKernelGGL(gru_traj_kernel, grid, block, 0, stream,
                       xg, W_ih, W_hh, b_ih, b_hh, W_enc, b_enc, out);
}

// Round 7
// 125.035 us; speedup vs baseline: 1.1161x; 1.1161x over previous
//
#include <hip/hip_runtime.h>

#define TT 200
#define NN 512
#define DD 4
#define HH 64
#define LL 32
#define SB 16                // sequences per block (fills MFMA M=16)
#define BPB (NN / SB)        // 32 blocks per batch
#define KP 72                // ushort pitch per h row (144B = 9*16B: b128-alignable)
#define LOG2E 1.44269504088896340736f

typedef short bf16x8 __attribute__((ext_vector_type(8)));
typedef float f32x4 __attribute__((ext_vector_type(4)));

union U8 { unsigned short s[8]; unsigned u[4]; bf16x8 v; };

// f32 -> (hi, lo) bf16 limbs by truncation: x = hi + lo + err, |err| <= 2^-16 |x|
__device__ __forceinline__ void split2(float x, unsigned short& hi, unsigned short& lo) {
    unsigned u = __float_as_uint(x);
    hi = (unsigned short)(u >> 16);
    float lf = x - __uint_as_float(u & 0xffff0000u);
    lo = (unsigned short)(__float_as_uint(lf) >> 16);
}

__global__ __launch_bounds__(256, 1)
void gru_traj_kernel(const float* __restrict__ xg,    // (B,T,N,D)
                     const float* __restrict__ W_ih,  // (192,4)
                     const float* __restrict__ W_hh,  // (192,64)
                     const float* __restrict__ b_ih,  // (192,)
                     const float* __restrict__ b_hh,  // (192,)
                     const float* __restrict__ W_enc, // (32,64)
                     const float* __restrict__ b_enc, // (32,)
                     float* __restrict__ out)         // (B,N,32)
{
    __shared__ __align__(16) float xall[TT][SB][DD];          // 51.2 KB, f32 x
    __shared__ __align__(16) unsigned short hhi[2][SB][KP];   // h hi-limbs (dbuf)
    __shared__ __align__(16) unsigned short hlo[2][SB][KP];   // h lo-limbs
    __shared__ __align__(16) float hsf[SB][HH + 4];           // f32 h for epilogue

    const int tid = threadIdx.x;
    const int bid = blockIdx.x;
    const int b   = bid >> 5;                // bid / BPB
    const int n0  = (bid & (BPB - 1)) * SB;

    const int w  = tid >> 6;     // wave -> gate tiles {w, w+4, w+8}: r,z,n for units 16w..16w+15
    const int l  = tid & 63;
    const int lr = l & 15;       // A-row / B-col / C-col within tile
    const int lg = l >> 4;       // k-group (A/B), row-group (C)

    // ---- prologue: preload whole x trajectory (f32) ----
    {
        float4* dst = reinterpret_cast<float4*>(&xall[0][0][0]);
        for (int f = tid; f < TT * 16; f += 256) {
            const int t = f >> 4, q = f & 15;
            dst[f] = *reinterpret_cast<const float4*>(
                xg + ((size_t)(b * TT + t) * NN + n0) * DD + q * 4);
        }
    }

    // ---- B fragments: W_hh^T tiles, prescaled (log2e / 2log2e), bf16 hi/lo limbs ----
    const float sc[3] = { LOG2E, LOG2E, 2.0f * LOG2E };
    bf16x8 bh[3][2], bl[3][2];
    #pragma unroll
    for (int i = 0; i < 3; ++i) {
        const int g = i * 64 + 16 * w + lr;
        #pragma unroll
        for (int kc = 0; kc < 2; ++kc) {
            const float* p = W_hh + g * HH + kc * 32 + lg * 8;
            U8 uh, ul;
            #pragma unroll
            for (int j = 0; j < 8; ++j) split2(p[j] * sc[i], uh.s[j], ul.s[j]);
            bh[i][kc] = uh.v; bl[i][kc] = ul.v;
        }
    }
    // per-lane gate constants (unit u = 16w + lr), prescaled
    float wih[3][4], cb[3];
    #pragma unroll
    for (int i = 0; i < 3; ++i) {
        const int g = i * 64 + 16 * w + lr;
        wih[i][0] = W_ih[g * DD + 0] * sc[i]; wih[i][1] = W_ih[g * DD + 1] * sc[i];
        wih[i][2] = W_ih[g * DD + 2] * sc[i]; wih[i][3] = W_ih[g * DD + 3] * sc[i];
        cb[i] = (i < 2) ? (b_ih[g] + b_hh[g]) * sc[i] : b_ih[g] * sc[i];
    }
    const float bn = b_hh[2 * 64 + 16 * w + lr] * sc[2];   // n-gate h-part bias (scaled)

    // ---- init: zero h limb buffers (h0 = 0) ----
    for (int idx = tid; idx < 2 * SB * KP / 2; idx += 256) {
        reinterpret_cast<unsigned*>(hhi)[idx] = 0u;
        reinterpret_cast<unsigned*>(hlo)[idx] = 0u;
    }
    float hreg[4] = {0.f, 0.f, 0.f, 0.f};   // h[s = lg*4+r][u = 16w+lr]
    __syncthreads();

    #pragma unroll 2
    for (int t = 0; t < TT; ++t) {
        const int cur = t & 1, nxt = cur ^ 1;

        // ---- A fragments: direct bf16-limb LDS loads ----
        bf16x8 ah0 = *reinterpret_cast<const bf16x8*>(&hhi[cur][lr][lg * 8]);
        bf16x8 ah1 = *reinterpret_cast<const bf16x8*>(&hhi[cur][lr][32 + lg * 8]);
        bf16x8 al0 = *reinterpret_cast<const bf16x8*>(&hlo[cur][lr][lg * 8]);
        bf16x8 al1 = *reinterpret_cast<const bf16x8*>(&hlo[cur][lr][32 + lg * 8]);

        // ---- gx (f32 VALU, prescaled; parallel on each SIMD, overlaps MFMA pipe) ----
        float gxv[3][4];
        #pragma unroll
        for (int r = 0; r < 4; ++r) {
            const int s = lg * 4 + r;
            float4 x4 = *reinterpret_cast<const float4*>(&xall[t][s][0]);
            #pragma unroll
            for (int i = 0; i < 3; ++i)
                gxv[i][r] = fmaf(wih[i][0], x4.x, fmaf(wih[i][1], x4.y,
                            fmaf(wih[i][2], x4.z, fmaf(wih[i][3], x4.w, cb[i]))));
        }

        // ---- 18 MFMAs: 6 chains (main depth 2, corr depth 4), shared zero C-init ----
        const f32x4 z4 = {0.f, 0.f, 0.f, 0.f};
        f32x4 aR  = __builtin_amdgcn_mfma_f32_16x16x32_bf16(ah0, bh[0][0], z4, 0,0,0);
        f32x4 aZ  = __builtin_amdgcn_mfma_f32_16x16x32_bf16(ah0, bh[1][0], z4, 0,0,0);
        f32x4 aN  = __builtin_amdgcn_mfma_f32_16x16x32_bf16(ah0, bh[2][0], z4, 0,0,0);
        f32x4 aRc = __builtin_amdgcn_mfma_f32_16x16x32_bf16(al0, bh[0][0], z4, 0,0,0);
        f32x4 aZc = __builtin_amdgcn_mfma_f32_16x16x32_bf16(al0, bh[1][0], z4, 0,0,0);
        f32x4 aNc = __builtin_amdgcn_mfma_f32_16x16x32_bf16(al0, bh[2][0], z4, 0,0,0);
        aR  = __builtin_amdgcn_mfma_f32_16x16x32_bf16(ah1, bh[0][1], aR , 0,0,0);
        aZ  = __builtin_amdgcn_mfma_f32_16x16x32_bf16(ah1, bh[1][1], aZ , 0,0,0);
        aN  = __builtin_amdgcn_mfma_f32_16x16x32_bf16(ah1, bh[2][1], aN , 0,0,0);
        aRc = __builtin_amdgcn_mfma_f32_16x16x32_bf16(al1, bh[0][1], aRc, 0,0,0);
        aZc = __builtin_amdgcn_mfma_f32_16x16x32_bf16(al1, bh[1][1], aZc, 0,0,0);
        aNc = __builtin_amdgcn_mfma_f32_16x16x32_bf16(al1, bh[2][1], aNc, 0,0,0);
        aRc = __builtin_amdgcn_mfma_f32_16x16x32_bf16(ah0, bl[0][0], aRc, 0,0,0);
        aZc = __builtin_amdgcn_mfma_f32_16x16x32_bf16(ah0, bl[1][0], aZc, 0,0,0);
        aNc = __builtin_amdgcn_mfma_f32_16x16x32_bf16(ah0, bl[2][0], aNc, 0,0,0);
        aRc = __builtin_amdgcn_mfma_f32_16x16x32_bf16(ah1, bl[0][1], aRc, 0,0,0);
        aZc = __builtin_amdgcn_mfma_f32_16x16x32_bf16(ah1, bl[1][1], aZc, 0,0,0);
        aNc = __builtin_amdgcn_mfma_f32_16x16x32_bf16(ah1, bl[2][1], aNc, 0,0,0);

        // ---- gates (exp2 domain, native transcendentals) + h update ----
        #pragma unroll
        for (int r = 0; r < 4; ++r) {
            const int s = lg * 4 + r;
            const int u = 16 * w + lr;
            float sR = (aR[r] + aRc[r]) + gxv[0][r];
            float sZ = (aZ[r] + aZc[r]) + gxv[1][r];
            float ghn = (aN[r] + aNc[r]) + bn;
            float rg = __builtin_amdgcn_rcpf(1.0f + __builtin_amdgcn_exp2f(-sR));
            float ez = __builtin_amdgcn_exp2f(-sZ);
            float na = fmaf(rg, ghn, gxv[2][r]);
            na = fminf(fmaxf(na, -44.0f), 44.0f);
            float e  = __builtin_amdgcn_exp2f(-na);
            float nn = (1.0f - e) * __builtin_amdgcn_rcpf(1.0f + e);
            float z  = __builtin_amdgcn_rcpf(1.0f + ez);
            float hn = fmaf(z, hreg[r] - nn, nn);       // (1-z)n + z h
            hreg[r] = hn;
            unsigned short hi, lo;
            split2(hn, hi, lo);
            hhi[nxt][s][u] = hi;
            hlo[nxt][s][u] = lo;
        }
        __syncthreads();   // h_{t+1} limbs visible; buf[cur] free next iteration
    }

    // ---- epilogue: out = h @ W_enc^T + b_enc (512 outputs, strided) ----
    #pragma unroll
    for (int r = 0; r < 4; ++r)
        hsf[lg * 4 + r][16 * w + lr] = hreg[r];
    __syncthreads();
    for (int o = tid; o < SB * LL; o += 256) {
        const int s = o >> 5, li = o & 31;
        float a = b_enc[li];
        #pragma unroll
        for (int k = 0; k < HH; ++k)
            a = fmaf(hsf[s][k], W_enc[li * HH + k], a);
        out[(bid * SB + s) * LL + li] = a;
    }
}

extern "C" void kernel_launch(void* const* d_in, const int* in_sizes, int n_in,
                              void* d_out, int out_size, void* d_ws, size_t ws_size,
                              hipStream_t stream) {
    const float* xg    = (const float*)d_in[0];
    const float* W_ih  = (const float*)d_in[1];
    const float* W_hh  = (const float*)d_in[2];
    const float* b_ih  = (const float*)d_in[3];
    const float* b_hh  = (const float*)d_in[4];
    const float* W_enc = (const float*)d_in[5];
    const float* b_enc = (const float*)d_in[6];
    float* out = (float*)d_out;

    dim3 grid(8 * BPB), block(256);   // 256 blocks -> exactly 1 block/CU
    hipLaunchKernelGGL(gru_traj_kernel, grid, block, 0, stream,
                       xg, W_ih, W_hh, b_ih, b_hh, W_enc, b_enc, out);
}